// Round 11
// baseline (2798.976 us; speedup 1.0000x reference)
//
#include <hip/hip_runtime.h>

#define SPIN_BOUND (1u << 21)
#define LDS_SPIN_BOUND (1u << 18)

typedef _Float16 h8 __attribute__((ext_vector_type(8)));
typedef float f4 __attribute__((ext_vector_type(4)));

__device__ __forceinline__ float sigf(float x) { return 1.f / (1.f + __expf(-x)); }
__device__ __forceinline__ float tanhfast(float x) { return 2.f / (1.f + __expf(-2.f * x)) - 1.f; }

#define MF(acc, a, b) acc = __builtin_amdgcn_mfma_f32_16x16x32_f16(a, b, acc, 0, 0, 0)

__device__ __forceinline__ void vm0() { asm volatile("s_waitcnt vmcnt(0)" ::: "memory"); }
__device__ __forceinline__ void l1inv() { asm volatile("buffer_inv sc0" ::: "memory"); }

// PROVEN poll mechanism (r7/r8/r9; r4/r6/r10 falsified all alternatives):
// producer = plain store after vmcnt(0) (write-through L1 -> shared XCD L2);
// consumer = buffer_inv sc0 + plain volatile load, EVERY poll iteration.
// sc0-scoped loads do NOT provide cross-CU visibility on gfx950 — do not retry.

// ---------------------------------------------------------------- prep kernels

__global__ void prep_conv(const float* __restrict__ in, const float* __restrict__ mlpw,
                          const float* __restrict__ adpw,
                          _Float16* __restrict__ seqX, _Float16* __restrict__ mlpW16,
                          _Float16* __restrict__ adpW16)
{
    const int NIN = 256 * 128 * 128;
    const int NM = 512 * 512;
    const int NA = 48 * 512;
    int i = blockIdx.x * blockDim.x + threadIdx.x;
    const int stride = gridDim.x * blockDim.x;
    for (; i < NIN + NM + NA; i += stride) {
        if (i < NIN) seqX[i] = (_Float16)in[i];
        else if (i < NIN + NM) mlpW16[i - NIN] = (_Float16)mlpw[i - NIN];
        else adpW16[i - NIN - NM] = (_Float16)adpw[i - NIN - NM];
    }
}

__global__ void prep_bias(const float* __restrict__ a0, const float* __restrict__ b0,
                          const float* __restrict__ a1, const float* __restrict__ b1,
                          const float* __restrict__ a2, const float* __restrict__ b2,
                          const float* __restrict__ a3, const float* __restrict__ b3,
                          float* __restrict__ biasSum)
{
    int i = blockIdx.x * blockDim.x + threadIdx.x;
    if (i >= 8192) return;
    const int c = i >> 11, j = i & 2047;
    const float* A = (c == 0) ? a0 : (c == 1) ? a1 : (c == 2) ? a2 : a3;
    const float* B = (c == 0) ? b0 : (c == 1) ? b1 : (c == 2) ? b2 : b3;
    biasSum[i] = A[j] + B[j];
}

// Wprep layout per cell: [p=32 col-groups][64 rows][K] fp16
__global__ void prep_w(const float* __restrict__ wih0, const float* __restrict__ whh0,
                       const float* __restrict__ wih1, const float* __restrict__ whh1,
                       const float* __restrict__ wih2, const float* __restrict__ whh2,
                       const float* __restrict__ wih3, const float* __restrict__ whh3,
                       _Float16* __restrict__ Wprep)
{
    const size_t N0 = (size_t)2048 * 640;
    const size_t N1 = (size_t)2048 * 1024;
    const size_t total = N0 + 3 * N1;
    size_t i = (size_t)blockIdx.x * blockDim.x + threadIdx.x;
    const size_t stride = (size_t)gridDim.x * blockDim.x;
    for (; i < total; i += stride) {
        int cell; size_t off;
        if (i < N0) { cell = 0; off = i; }
        else { cell = 1 + (int)((i - N0) / N1); off = (i - N0) % N1; }
        const int K = cell ? 1024 : 640;
        const int Din = cell ? 512 : 128;
        const int k = (int)(off % K);
        const int rowIdx = (int)(off / K);
        const int p = rowIdx >> 6;
        const int row64 = rowIdx & 63;
        const int q = row64 >> 4;
        const int gRow = q * 512 + p * 16 + (row64 & 15);
        const float* wih = (cell == 0) ? wih0 : (cell == 1) ? wih1 : (cell == 2) ? wih2 : wih3;
        const float* whh = (cell == 0) ? whh0 : (cell == 1) ? whh1 : (cell == 2) ? whh2 : whh3;
        const float v = (k < Din) ? wih[(size_t)gRow * Din + k]
                                  : whh[(size_t)gRow * 512 + (k - Din)];
        Wprep[i] = (_Float16)v;
    }
}

// ---------------------------------------------------------------- per-cell body
// One kernel per cell (stream order = cross-XCD handoff; per-cell rocprof rows).
// Every cell: NCOMP compute waves + 1 dedicated poller wave. Poller runs the
// proven l1inv+load poll over all nMt flag lines of its rg, then broadcasts the
// step generation via an LDS word; compute waves spin on LDS only (no cache
// maintenance on compute waves at all).

template<int CELL, int TPBC>
__device__ __forceinline__ void cell_body(
    const _Float16* __restrict__ src, _Float16* __restrict__ dst,
    const _Float16* __restrict__ wbase, const float* __restrict__ biasSum,
    unsigned* __restrict__ cellFlags, unsigned* __restrict__ cellCnt, char* smem)
{
    constexpr int Din = (CELL == 0) ? 128 : 512;
    constexpr int K = Din + 512;
    constexpr int Bd = 128 << CELL;
    constexpr int Td = 256 >> CELL;
    constexpr int r = Bd >> 3;
    constexpr int nMt = r >> 4;            // 1,2,4,8
    constexpr int ldsRow = K * 2;
    constexpr int NKX = Din >> 5;          // 4 or 16
    constexpr bool RED = (CELL < 3);       // K-split wave pairs + LDS reduce
    constexpr int NXW = RED ? (NKX / 2) : NKX;
    constexpr int NCOMP = RED ? (2 * nMt) : nMt;   // compute waves: 2,4,8,8
    constexpr int pollW = NCOMP;                    // dedicated poller wave

    const int tid = threadIdx.x;
    const int lane = tid & 63;
    const int wave = tid >> 6;
    const int colsel = lane & 15;
    const int kq = lane >> 4;

    volatile unsigned* ldsGen = (volatile unsigned*)(smem + 64 * ldsRow + 16384);
    unsigned* s_flag = (unsigned*)(smem + 64 * ldsRow + 16384 + 64);

    // XCD self-assign: rg == physical XCD (shared L2 by construction);
    // LDS > 80KB forces 1 block/CU -> exactly 32 blocks per XCD.
    if (tid == 0) {
        unsigned xcc;
        asm volatile("s_getreg_b32 %0, hwreg(HW_REG_XCC_ID)" : "=s"(xcc));
        xcc &= 7u;
        unsigned slot = __hip_atomic_fetch_add(cellCnt + 64u * xcc, 1u,
                                               __ATOMIC_RELAXED, __HIP_MEMORY_SCOPE_AGENT);
        s_flag[0] = (xcc << 5) | (slot & 31u);
        *ldsGen = 0u;
    }
    __syncthreads();
    const unsigned rgp = s_flag[0];
    __syncthreads();
    const int rg = rgp >> 5;
    const int p = rgp & 31;
    const int rowBase = rg * r;

    // stage W slice (64 rows x K fp16) into LDS, XOR-swizzled
    {
        const _Float16* wsl = wbase + (size_t)p * 64 * K;
        constexpr int kcN = K >> 3;
        for (int i = tid; i < 64 * kcN; i += TPBC) {
            const int row = i / kcN;
            const int kc = i - row * kcN;
            h8 v = *(const h8*)(wsl + (size_t)row * K + (kc << 3));
            *(h8*)(smem + row * ldsRow + ((kc << 4) ^ ((row & 7) << 4))) = v;
        }
    }
    __syncthreads();

    const int mt = RED ? (wave >> 1) : wave;
    const int kh = RED ? (wave & 1) : 0;
    const bool busy = (wave < NCOMP);

    const int xlo = (RED && kh) ? (NKX / 2) : 0;
    const int hlo = (RED && kh) ? 8 : 0;

    const float bq0 = biasSum[CELL * 2048 + 0 * 512 + p * 16 + colsel];
    const float bq1 = biasSum[CELL * 2048 + 1 * 512 + p * 16 + colsel];
    const float bq2 = biasSum[CELL * 2048 + 2 * 512 + p * 16 + colsel];
    const float bq3 = biasSum[CELL * 2048 + 3 * 512 + p * 16 + colsel];

    const int arow = rowBase + mt * 16 + colsel;
    const int hcol = p * 16 + colsel;

    unsigned* myFlag = cellFlags + (rg * 8 + mt) * 256 + p * 8;
    float* scr = (float*)(smem + (size_t)64 * ldsRow);

    float cr[4] = {0.f, 0.f, 0.f, 0.f};
    bool dead = false;
    h8 xr[NXW];
    h8 hr0[8];

    auto ldB = [&](int kbyte, int rrow) -> h8 {
        return *(const h8*)(smem + rrow * ldsRow + (kbyte ^ ((rrow & 7) << 4)));
    };

    // poller: wait all nMt lines of this rg (2 lines per pass via lane halves)
    auto poll_lines = [&](unsigned target) -> bool {
        #pragma unroll
        for (int l0 = 0; l0 < nMt; l0 += 2) {
            int li = (nMt == 1) ? 0 : (l0 + (lane >> 5));
            if (li >= nMt) li = nMt - 1;
            const volatile unsigned* fp =
                (const volatile unsigned*)(cellFlags + (rg * 8 + li) * 256 + (lane & 31) * 8);
            unsigned n = 0;
            for (;;) {
                l1inv();
                if (__all((int)(*fp >= target))) break;
                __builtin_amdgcn_s_sleep(1);
                if (++n > SPIN_BOUND) return false;
            }
        }
        return true;
    };
    auto spin_gen = [&](unsigned target) {
        unsigned n = 0;
        while (*ldsGen < target) { if (++n > LDS_SPIN_BOUND) break; }
        asm volatile("" ::: "memory");
    };

    auto x_issue = [&](int t) {
        const _Float16* ap = src + (size_t)t * Bd * Din + (size_t)arow * Din + (kq << 3);
        #pragma unroll
        for (int i = 0; i < NXW; ++i)
            xr[i] = *(const h8*)(ap + ((xlo + i) << 5));
    };
    auto x_compute = [&](f4 (&C)[4]) {
        #pragma unroll
        for (int g = 0; g < 4; ++g) C[g] = (f4){0.f, 0.f, 0.f, 0.f};
        #pragma unroll
        for (int i = 0; i < NXW; ++i) {
            const int kbyte = (((xlo + i) << 5) + (kq << 3)) << 1;
            h8 bf0 = ldB(kbyte, colsel);
            h8 bf1 = ldB(kbyte, 16 + colsel);
            h8 bf2 = ldB(kbyte, 32 + colsel);
            h8 bf3 = ldB(kbyte, 48 + colsel);
            MF(C[0], xr[i], bf0); MF(C[1], xr[i], bf1);
            MF(C[2], xr[i], bf2); MF(C[3], xr[i], bf3);
        }
    };
    auto h_issue0 = [&](int t) {
        const _Float16* ap = dst + (size_t)(t - 1) * Bd * 512 + (size_t)arow * 512 + (kq << 3);
        #pragma unroll
        for (int i = 0; i < 8; ++i)
            hr0[i] = *(const h8*)(ap + ((hlo + i) << 5));
    };
    auto h_compute = [&](int t, f4 (&C)[4]) {
        #pragma unroll
        for (int i = 0; i < 8; ++i) {
            const int kbyte = (Din + ((hlo + i) << 5) + (kq << 3)) << 1;
            h8 bf0 = ldB(kbyte, colsel);
            h8 bf1 = ldB(kbyte, 16 + colsel);
            h8 bf2 = ldB(kbyte, 32 + colsel);
            h8 bf3 = ldB(kbyte, 48 + colsel);
            MF(C[0], hr0[i], bf0); MF(C[1], hr0[i], bf1);
            MF(C[2], hr0[i], bf2); MF(C[3], hr0[i], bf3);
        }
        if constexpr (!RED) {   // cell3: second batch of 8 ks
            const _Float16* ap = dst + (size_t)(t - 1) * Bd * 512 + (size_t)arow * 512 + (kq << 3);
            h8 hr1[8];
            #pragma unroll
            for (int i = 0; i < 8; ++i)
                hr1[i] = *(const h8*)(ap + ((8 + i) << 5));
            #pragma unroll
            for (int i = 0; i < 8; ++i) {
                const int kbyte = (Din + ((8 + i) << 5) + (kq << 3)) << 1;
                h8 bf0 = ldB(kbyte, colsel);
                h8 bf1 = ldB(kbyte, 16 + colsel);
                h8 bf2 = ldB(kbyte, 32 + colsel);
                h8 bf3 = ldB(kbyte, 48 + colsel);
                MF(C[0], hr1[i], bf0); MF(C[1], hr1[i], bf1);
                MF(C[2], hr1[i], bf2); MF(C[3], hr1[i], bf3);
            }
        }
    };
    auto writeScr = [&](f4 (&C)[4]) {
        #pragma unroll
        for (int g = 0; g < 4; ++g)
            *(f4*)(scr + (size_t)((mt * 4 + g) * 64 + lane) * 4) = C[g];
    };
    auto finish = [&](int t, f4 (&C)[4]) {
        if constexpr (RED) {
            #pragma unroll
            for (int g = 0; g < 4; ++g)
                C[g] += *(const f4*)(scr + (size_t)((mt * 4 + g) * 64 + lane) * 4);
        }
        const size_t rb = (size_t)t * Bd + rowBase + mt * 16 + kq * 4;
        #pragma unroll
        for (int j = 0; j < 4; ++j) {
            const float gi = C[0][j] + bq0;
            const float gf = C[1][j] + bq1;
            const float gg = C[2][j] + bq2;
            const float go = C[3][j] + bq3;
            const float cc = sigf(gf) * cr[j] + sigf(gi) * tanhfast(gg);
            const float hh = sigf(go) * tanhfast(cc);
            cr[j] = cc;
            dst[(rb + j) * 512 + hcol] = (_Float16)hh;
        }
        vm0();
        if (lane == 0) *(volatile unsigned*)myFlag = (unsigned)(t + 1);
    };

    f4 acc[4];
    if (busy) x_issue(0);

    for (int t = 0; t < Td; ++t) {
        if (t > 0) {
            if (wave == pollW) {
                if (!dead) dead = !poll_lines((unsigned)t);
                if (lane == 0) *ldsGen = (unsigned)t;
            } else if (busy) {
                spin_gen((unsigned)t);
                h_issue0(t);
            }
        }
        if (busy) {
            x_compute(acc);
            if (t > 0) h_compute(t, acc);
        }
        if constexpr (RED) {
            if (busy && kh == 1) writeScr(acc);
            __syncthreads();
        }
        if (busy && kh == 0) finish(t, acc);
        if (busy && t + 1 < Td) x_issue(t + 1);
    }
}

// ---------------------------------------------------------------- cell kernels

#define CELL_KARGS const _Float16* __restrict__ src, _Float16* __restrict__ dst, \
                   const _Float16* __restrict__ wbase, const float* __restrict__ biasSum, \
                   unsigned* __restrict__ cellFlags, unsigned* __restrict__ cellCnt

__global__ __launch_bounds__(256) void drnn_cell0(CELL_KARGS) {
    extern __shared__ char smem[];
    cell_body<0, 256>(src, dst, wbase, biasSum, cellFlags, cellCnt, smem);
}
__global__ __launch_bounds__(384) void drnn_cell1(CELL_KARGS) {
    extern __shared__ char smem[];
    cell_body<1, 384>(src, dst, wbase, biasSum, cellFlags, cellCnt, smem);
}
__global__ __launch_bounds__(576) void drnn_cell2(CELL_KARGS) {
    extern __shared__ char smem[];
    cell_body<2, 576>(src, dst, wbase, biasSum, cellFlags, cellCnt, smem);
}
__global__ __launch_bounds__(576) void drnn_cell3(CELL_KARGS) {
    extern __shared__ char smem[];
    cell_body<3, 576>(src, dst, wbase, biasSum, cellFlags, cellCnt, smem);
}

// ---------------------------------------------------------------- head

__global__ __launch_bounds__(256) void head_kernel(
    const _Float16* __restrict__ seq1,
    const _Float16* __restrict__ seq3,
    const _Float16* __restrict__ mlpW16,
    const float* __restrict__ mlp_b,
    const _Float16* __restrict__ adpW16,
    const float* __restrict__ adp_b,
    float* __restrict__ out)
{
    extern __shared__ char smem[];   // y1 tile [64][512] fp16, XOR-swizzled
    const int tid = threadIdx.x;
    const int lane = tid & 63, wave = tid >> 6;
    const int colsel = lane & 15, kq = lane >> 4;
    const size_t row0 = (size_t)blockIdx.x * 64 + wave * 16;

    h8 aR[16];
    {
        const size_t ar = (row0 + colsel) * 512;
        #pragma unroll
        for (int ks = 0; ks < 16; ++ks) {
            const int kb = ks * 32 + kq * 8;
            h8 a1 = *(const h8*)(seq1 + ar + kb);
            h8 a3 = *(const h8*)(seq3 + ar + kb);
            aR[ks] = a1 + a3;
        }
    }
    for (int nt = 0; nt < 32; ++nt) {
        f4 acc = {0.f, 0.f, 0.f, 0.f};
        const int brow = nt * 16 + colsel;
        #pragma unroll
        for (int ks = 0; ks < 16; ++ks) {
            const int kb = ks * 32 + kq * 8;
            h8 b = *(const h8*)(mlpW16 + (size_t)brow * 512 + kb);
            acc = __builtin_amdgcn_mfma_f32_16x16x32_f16(aR[ks], b, acc, 0, 0, 0);
        }
        const int n = nt * 16 + colsel;
        const float bn = mlp_b[n];
        const int lrow0 = wave * 16 + kq * 4;
        #pragma unroll
        for (int j = 0; j < 4; ++j) {
            const float y = tanhfast(acc[j] + bn);
            const int row = lrow0 + j;
            *(_Float16*)(smem + row * 1024 + ((n * 2) ^ ((row & 7) << 4))) = (_Float16)y;
        }
    }
    __syncthreads();
    f4 acc0 = {0.f,0.f,0.f,0.f}, acc1 = {0.f,0.f,0.f,0.f}, acc2 = {0.f,0.f,0.f,0.f};
    const int arow = wave * 16 + colsel;
    #pragma unroll
    for (int ks = 0; ks < 16; ++ks) {
        const int kb = ks * 32 + kq * 8;
        h8 a = *(const h8*)(smem + arow * 1024 + ((kb * 2) ^ ((arow & 7) << 4)));
        h8 b0 = *(const h8*)(adpW16 + (size_t)(colsel) * 512 + kb);
        h8 b1 = *(const h8*)(adpW16 + (size_t)(16 + colsel) * 512 + kb);
        h8 b2 = *(const h8*)(adpW16 + (size_t)(32 + colsel) * 512 + kb);
        acc0 = __builtin_amdgcn_mfma_f32_16x16x32_f16(a, b0, acc0, 0, 0, 0);
        acc1 = __builtin_amdgcn_mfma_f32_16x16x32_f16(a, b1, acc1, 0, 0, 0);
        acc2 = __builtin_amdgcn_mfma_f32_16x16x32_f16(a, b2, acc2, 0, 0, 0);
    }
    const size_t orow0 = row0 + kq * 4;
    #pragma unroll
    for (int j = 0; j < 4; ++j) {
        out[(orow0 + j) * 48 + colsel]      = acc0[j] + adp_b[colsel];
        out[(orow0 + j) * 48 + 16 + colsel] = acc1[j] + adp_b[16 + colsel];
        out[(orow0 + j) * 48 + 32 + colsel] = acc2[j] + adp_b[32 + colsel];
    }
}

// ---------------------------------------------------------------- launch

extern "C" void kernel_launch(void* const* d_in, const int* in_sizes, int n_in,
                              void* d_out, int out_size, void* d_ws, size_t ws_size,
                              hipStream_t stream)
{
    (void)in_sizes; (void)n_in; (void)out_size; (void)ws_size;
    const float* input = (const float*)d_in[0];
    const float* Wih[4]; const float* Whh[4]; const float* Bih[4]; const float* Bhh[4];
    for (int i = 0; i < 4; ++i) {
        Wih[i] = (const float*)d_in[1 + 4 * i];
        Whh[i] = (const float*)d_in[2 + 4 * i];
        Bih[i] = (const float*)d_in[3 + 4 * i];
        Bhh[i] = (const float*)d_in[4 + 4 * i];
    }
    const float* mlpw = (const float*)d_in[17];
    const float* mlpb = (const float*)d_in[18];
    const float* adpw = (const float*)d_in[19];
    const float* adpb = (const float*)d_in[20];
    float* out = (float*)d_out;

    char* ws = (char*)d_ws;
    size_t off = 0;
    auto alloc = [&](size_t bytes) -> char* {
        char* ptr = ws + off;
        off += (bytes + 255) & ~(size_t)255;
        return ptr;
    };
    // sync layout (dwords): [512..2559] per-cell XCD counters (cell*512 + xcc*64)
    //                       [4096..69631] flags: cell*16384 + (rg*8+mt)*256 + p*8
    const size_t SYNC_BYTES = (size_t)(4096 + 4 * 16384) * 4;
    unsigned* syncc   = (unsigned*)alloc(SYNC_BYTES);
    _Float16* seqX    = (_Float16*)alloc((size_t)32768 * 128 * 2);
    _Float16* seq0    = (_Float16*)alloc((size_t)32768 * 512 * 2);
    _Float16* seq1    = (_Float16*)alloc((size_t)32768 * 512 * 2);
    _Float16* seq2    = (_Float16*)alloc((size_t)32768 * 512 * 2);
    _Float16* seq3    = (_Float16*)alloc((size_t)32768 * 512 * 2);
    _Float16* Wprep   = (_Float16*)alloc((size_t)2048 * 3712 * 2);
    float*    biasSum = (float*)alloc(8192 * 4);
    _Float16* mlpW16  = (_Float16*)alloc((size_t)262144 * 2);
    _Float16* adpW16  = (_Float16*)alloc((size_t)24576 * 2);

    unsigned* cnts  = syncc + 512;
    unsigned* flags = syncc + 4096;

    hipMemsetAsync(syncc, 0, SYNC_BYTES, stream);
    prep_conv<<<2048, 256, 0, stream>>>(input, mlpw, adpw, seqX, mlpW16, adpW16);
    prep_bias<<<32, 256, 0, stream>>>(Bih[0], Bhh[0], Bih[1], Bhh[1],
                                      Bih[2], Bhh[2], Bih[3], Bhh[3], biasSum);
    prep_w<<<4096, 256, 0, stream>>>(Wih[0], Whh[0], Wih[1], Whh[1],
                                     Wih[2], Whh[2], Wih[3], Whh[3], Wprep);

    // LDS: 64*K*2 (W) + 16384 (scratch) + 128 (gen+assign); >80KB forces 1 block/CU
    const int lds0 = 64 * 1280 + 16384 + 128;    //  98,432
    const int lds1 = 64 * 2048 + 16384 + 128;    // 147,584
    hipFuncSetAttribute((const void*)drnn_cell0, hipFuncAttributeMaxDynamicSharedMemorySize, lds0);
    hipFuncSetAttribute((const void*)drnn_cell1, hipFuncAttributeMaxDynamicSharedMemorySize, lds1);
    hipFuncSetAttribute((const void*)drnn_cell2, hipFuncAttributeMaxDynamicSharedMemorySize, lds1);
    hipFuncSetAttribute((const void*)drnn_cell3, hipFuncAttributeMaxDynamicSharedMemorySize, lds1);
    hipFuncSetAttribute((const void*)head_kernel, hipFuncAttributeMaxDynamicSharedMemorySize, 65536);

    drnn_cell0<<<256, 256, lds0, stream>>>(seqX, seq0, Wprep, biasSum,
                                           flags + 0 * 16384, cnts + 0 * 512);
    drnn_cell1<<<256, 384, lds1, stream>>>(seq0, seq1, Wprep + (size_t)2048 * 640, biasSum,
                                           flags + 1 * 16384, cnts + 1 * 512);
    drnn_cell2<<<256, 576, lds1, stream>>>(seq1, seq2, Wprep + (size_t)2048 * 1664, biasSum,
                                           flags + 2 * 16384, cnts + 2 * 512);
    drnn_cell3<<<256, 576, lds1, stream>>>(seq2, seq3, Wprep + (size_t)2048 * 2688, biasSum,
                                           flags + 3 * 16384, cnts + 3 * 512);
    head_kernel<<<512, 256, 65536, stream>>>(seq1, seq3, mlpW16, mlpb, adpW16, adpb, out);
}